// Round 1
// baseline (747.778 us; speedup 1.0000x reference)
//
#include <hip/hip_runtime.h>
#include <stdint.h>

typedef unsigned short u16;
typedef __bf16 bf16x8 __attribute__((ext_vector_type(8)));
typedef float  f32x4  __attribute__((ext_vector_type(4)));

#define N_TOK 8192
#define DIM   2048
#define NEXP  8

// ws layout (bytes)
#define OFF_CNT 0
#define OFF_IDX 256
#define OFF_W   (OFF_IDX + NEXP * N_TOK * 4)          // 262400
#define OFF_X   (OFF_W + NEXP * N_TOK * 4)            // 524544 (256-aligned)
#define OFF_WET (OFF_X + (size_t)N_TOK * DIM * 2)     // +33.5MB
// total = OFF_WET + 8*2048*2048*2 ~= 101.2 MB

__device__ __forceinline__ u16 f2bf(float f) {
    unsigned int u = __float_as_uint(f);
    u = (u + 0x7FFFu + ((u >> 16) & 1u)) >> 16;   // RNE; inputs are finite
    return (u16)u;
}

__device__ __forceinline__ void gload16(const void* g, void* l) {
    __builtin_amdgcn_global_load_lds(
        (const __attribute__((address_space(1))) unsigned int*)g,
        (__attribute__((address_space(3))) unsigned int*)l,
        16, 0, 0);
}

// ---- kernel 1: inputs fp32 -> bf16 ------------------------------------
__global__ void k_convert_x(const float* __restrict__ x, u16* __restrict__ xb) {
    size_t i = ((size_t)blockIdx.x * 256 + threadIdx.x) * 8;
    const float4* p = (const float4*)(x + i);
    float4 a = p[0], b = p[1];
    uint4 o;
    o.x = (unsigned)f2bf(a.x) | ((unsigned)f2bf(a.y) << 16);
    o.y = (unsigned)f2bf(a.z) | ((unsigned)f2bf(a.w) << 16);
    o.z = (unsigned)f2bf(b.x) | ((unsigned)f2bf(b.y) << 16);
    o.w = (unsigned)f2bf(b.z) | ((unsigned)f2bf(b.w) << 16);
    *(uint4*)(xb + i) = o;
}

// ---- kernel 2: We[e][k][n] fp32 -> We_t[e][n][k] bf16 ------------------
__global__ void k_transpose_we(const float* __restrict__ We, u16* __restrict__ Wt) {
    __shared__ float t[64][65];
    int e = blockIdx.z, k0 = blockIdx.y * 64, n0 = blockIdx.x * 64;
    const float* src = We + ((size_t)e * DIM + k0) * DIM + n0;
    for (int i = threadIdx.x; i < 4096; i += 256) {
        int r = i >> 6, c = i & 63;
        t[r][c] = src[(size_t)r * DIM + c];
    }
    __syncthreads();
    u16* dst = Wt + ((size_t)e * DIM + n0) * DIM + k0;
    for (int i = threadIdx.x; i < 4096; i += 256) {
        int n = i >> 6, k = i & 63;
        dst[(size_t)n * DIM + k] = f2bf(t[k][n]);
    }
}

// ---- kernel 3: gate (fp64 logits), top-2, softmax, expert lists --------
__global__ void k_gate(const float* __restrict__ x, const float* __restrict__ Wg,
                       int* __restrict__ cnt, int* __restrict__ tok_idx,
                       float* __restrict__ tok_w) {
    int wave = threadIdx.x >> 6, lane = threadIdx.x & 63;
    int n = blockIdx.x * 4 + wave;
    const float* xr = x + (size_t)n * DIM;
    double acc[8] = {0, 0, 0, 0, 0, 0, 0, 0};
    for (int d = lane; d < DIM; d += 64) {
        float xv = xr[d];
        const float4* wg = (const float4*)(Wg + d * 8);
        float4 w0 = wg[0], w1 = wg[1];
        acc[0] += (double)xv * (double)w0.x;
        acc[1] += (double)xv * (double)w0.y;
        acc[2] += (double)xv * (double)w0.z;
        acc[3] += (double)xv * (double)w0.w;
        acc[4] += (double)xv * (double)w1.x;
        acc[5] += (double)xv * (double)w1.y;
        acc[6] += (double)xv * (double)w1.z;
        acc[7] += (double)xv * (double)w1.w;
    }
#pragma unroll
    for (int off = 32; off; off >>= 1)
#pragma unroll
        for (int e = 0; e < 8; e++) acc[e] += __shfl_xor(acc[e], off);
    if (lane == 0) {
        float v[8];
#pragma unroll
        for (int e = 0; e < 8; e++) v[e] = (float)acc[e];
        int e0 = 0; float v0 = v[0];
#pragma unroll
        for (int e = 1; e < 8; e++) if (v[e] > v0) { v0 = v[e]; e0 = e; }
        int e1 = -1; float v1 = -1e30f;
#pragma unroll
        for (int e = 0; e < 8; e++) if (e != e0 && v[e] > v1) { v1 = v[e]; e1 = e; }
        float ex = expf(v1 - v0);             // <= 1, stable
        float w0 = 1.0f / (1.0f + ex);
        float w1 = ex / (1.0f + ex);
        int p0 = atomicAdd(&cnt[e0], 1);
        tok_idx[e0 * N_TOK + p0] = n; tok_w[e0 * N_TOK + p0] = w0;
        int p1 = atomicAdd(&cnt[e1], 1);
        tok_idx[e1 * N_TOK + p1] = n; tok_w[e1 * N_TOK + p1] = w1;
    }
}

// ---- kernel 4: grouped gather-GEMM + scaled scatter-add ----------------
// BM=128, BN=128, BK=32; 4 waves, each does a 64x64 subtile (4x4 mfma 16x16x32)
__global__ __launch_bounds__(256) void k_moe_gemm(
    const u16* __restrict__ Xb, const u16* __restrict__ Wt,
    const float* __restrict__ be, const int* __restrict__ cnt,
    const int* __restrict__ tok_idx, const float* __restrict__ tok_w,
    float* __restrict__ out) {
    int e = blockIdx.z;
    int m0 = blockIdx.y * 128;
    int n0 = blockIdx.x * 128;
    int count = cnt[e];
    if (m0 >= count) return;

    __shared__ u16 As[128 * 32];
    __shared__ u16 Bs[128 * 32];

    int tid = threadIdx.x;
    int wave = tid >> 6, lane = tid & 63;

    // staging pattern: each wave stages 16 rows/round (lane>>2 = row, lane&3 = 16B chunk)
    int srow = wave * 16 + (lane >> 2);
    int scol = (lane & 3) * 8;  // element offset within row
    int ta0 = tok_idx[e * N_TOK + m0 + srow] & (N_TOK - 1);        // mask: rows past count hold poison
    int ta1 = tok_idx[e * N_TOK + m0 + srow + 64] & (N_TOK - 1);
    const u16* gA0 = Xb + (size_t)ta0 * DIM + scol;
    const u16* gA1 = Xb + (size_t)ta1 * DIM + scol;
    const u16* gB0 = Wt + ((size_t)e * DIM + n0 + srow) * DIM + scol;
    const u16* gB1 = Wt + ((size_t)e * DIM + n0 + srow + 64) * DIM + scol;
    u16* lA0 = As + (wave * 16) * 32;        // wave-uniform LDS bases
    u16* lA1 = As + (64 + wave * 16) * 32;
    u16* lB0 = Bs + (wave * 16) * 32;
    u16* lB1 = Bs + (64 + wave * 16) * 32;

    int wr = (wave >> 1) * 64, wc = (wave & 1) * 64;
    int q = lane >> 4, mr = lane & 15;

    f32x4 acc[4][4] = {};

    for (int kk = 0; kk < DIM; kk += 32) {
        gload16(gA0 + kk, lA0);
        gload16(gA1 + kk, lA1);
        gload16(gB0 + kk, lB0);
        gload16(gB1 + kk, lB1);
        __syncthreads();
        bf16x8 af[4], bfr[4];
#pragma unroll
        for (int i = 0; i < 4; i++)
            af[i] = *(const bf16x8*)(As + (wr + i * 16 + mr) * 32 + q * 8);
#pragma unroll
        for (int j = 0; j < 4; j++)
            bfr[j] = *(const bf16x8*)(Bs + (wc + j * 16 + mr) * 32 + q * 8);
#pragma unroll
        for (int i = 0; i < 4; i++)
#pragma unroll
            for (int j = 0; j < 4; j++)
                acc[i][j] = __builtin_amdgcn_mfma_f32_16x16x32_bf16(
                    af[i], bfr[j], acc[i][j], 0, 0, 0);
        __syncthreads();
    }

    // epilogue: C/D layout col=lane&15, row=(lane>>4)*4+reg
    float bev[4];
#pragma unroll
    for (int j = 0; j < 4; j++) bev[j] = be[e * DIM + n0 + wc + j * 16 + mr];
#pragma unroll
    for (int i = 0; i < 4; i++) {
#pragma unroll
        for (int r = 0; r < 4; r++) {
            int row = wr + i * 16 + q * 4 + r;
            int gr = m0 + row;
            if (gr < count) {
                int t = tok_idx[e * N_TOK + gr];
                float w = tok_w[e * N_TOK + gr];
                float* orow = out + (size_t)t * DIM + n0 + wc + mr;
#pragma unroll
                for (int j = 0; j < 4; j++)
                    atomicAdd(orow + j * 16, w * (acc[i][j][r] + bev[j]));
            }
        }
    }
}

extern "C" void kernel_launch(void* const* d_in, const int* in_sizes, int n_in,
                              void* d_out, int out_size, void* d_ws, size_t ws_size,
                              hipStream_t stream) {
    const float* x  = (const float*)d_in[0];   // [N, D]
    const float* Wg = (const float*)d_in[1];   // [D, E]
    const float* We = (const float*)d_in[2];   // [E, D, D]
    const float* be = (const float*)d_in[3];   // [E, D]
    float* out = (float*)d_out;                // [N, D] fp32
    char* ws = (char*)d_ws;
    int*   cnt     = (int*)(ws + OFF_CNT);
    int*   tok_idx = (int*)(ws + OFF_IDX);
    float* tok_w   = (float*)(ws + OFF_W);
    u16*   Xb      = (u16*)(ws + OFF_X);
    u16*   Wt      = (u16*)(ws + OFF_WET);

    hipMemsetAsync(cnt, 0, 256, stream);
    hipMemsetAsync(out, 0, (size_t)N_TOK * DIM * 4, stream);
    k_convert_x<<<N_TOK * DIM / (256 * 8), 256, 0, stream>>>(x, Xb);
    k_transpose_we<<<dim3(DIM / 64, DIM / 64, NEXP), 256, 0, stream>>>(We, Wt);
    k_gate<<<N_TOK / 4, 256, 0, stream>>>(x, Wg, cnt, tok_idx, tok_w);
    k_moe_gemm<<<dim3(DIM / 128, N_TOK / 128, NEXP), 256, 0, stream>>>(
        Xb, Wt, be, cnt, tok_idx, tok_w, out);
}

// Round 2
// 745.077 us; speedup vs baseline: 1.0036x; 1.0036x over previous
//
#include <hip/hip_runtime.h>
#include <stdint.h>

typedef unsigned short u16;
typedef __bf16 bf16x8 __attribute__((ext_vector_type(8)));
typedef float  f32x4  __attribute__((ext_vector_type(4)));

#define N_TOK 8192
#define DIM   2048
#define NEXP  8
#define RPAD  17408   // 136*128 >= 2*N_TOK + 8*127 rounded up

// ---- ws layout (bytes) ----
#define OFF_CNT   0                               // int[8]
#define OFF_BASE  256                             // int[9]
#define OFF_RI    512                             // int4[N_TOK]   (e0,e1,p0,p1)
#define OFF_RW    (OFF_RI + N_TOK * 16)           // float2[N_TOK]
#define OFF_TIDX  (OFF_RW + N_TOK * 8)            // int[RPAD]
#define OFF_TW    (OFF_TIDX + RPAD * 4)           // float[RPAD]
#define OFF_XP    336384                          // u16[RPAD*DIM]  (512-aligned)
#define OFF_WT    (OFF_XP + (size_t)RPAD * DIM * 2)  // u16[NEXP*DIM*DIM]
// total ~138.8 MB

__device__ __forceinline__ u16 f2bf(float f) {
    unsigned int u = __float_as_uint(f);
    u = (u + 0x7FFFu + ((u >> 16) & 1u)) >> 16;   // RNE; inputs finite
    return (u16)u;
}

__device__ __forceinline__ void gload16(const void* g, void* l) {
    __builtin_amdgcn_global_load_lds(
        (const __attribute__((address_space(1))) unsigned int*)g,
        (__attribute__((address_space(3))) unsigned int*)l,
        16, 0, 0);
}

// ---- gate: fp64 logits, top-2, softmax, per-expert slot assignment -----
__global__ void k_gate(const float* __restrict__ x, const float* __restrict__ Wg,
                       int* __restrict__ cnt, int4* __restrict__ route_i,
                       float2* __restrict__ route_w) {
    int wave = threadIdx.x >> 6, lane = threadIdx.x & 63;
    int n = blockIdx.x * 4 + wave;
    const float* xr = x + (size_t)n * DIM;
    double acc[8] = {0, 0, 0, 0, 0, 0, 0, 0};
    for (int d = lane; d < DIM; d += 64) {
        float xv = xr[d];
        const float4* wg = (const float4*)(Wg + d * 8);
        float4 w0 = wg[0], w1 = wg[1];
        acc[0] += (double)xv * (double)w0.x;
        acc[1] += (double)xv * (double)w0.y;
        acc[2] += (double)xv * (double)w0.z;
        acc[3] += (double)xv * (double)w0.w;
        acc[4] += (double)xv * (double)w1.x;
        acc[5] += (double)xv * (double)w1.y;
        acc[6] += (double)xv * (double)w1.z;
        acc[7] += (double)xv * (double)w1.w;
    }
#pragma unroll
    for (int off = 32; off; off >>= 1)
#pragma unroll
        for (int e = 0; e < 8; e++) acc[e] += __shfl_xor(acc[e], off);
    if (lane == 0) {
        float v[8];
#pragma unroll
        for (int e = 0; e < 8; e++) v[e] = (float)acc[e];
        int e0 = 0; float v0 = v[0];
#pragma unroll
        for (int e = 1; e < 8; e++) if (v[e] > v0) { v0 = v[e]; e0 = e; }
        int e1 = -1; float v1 = -1e30f;
#pragma unroll
        for (int e = 0; e < 8; e++) if (e != e0 && v[e] > v1) { v1 = v[e]; e1 = e; }
        float ex = expf(v1 - v0);             // <= 1, stable
        float w0 = 1.0f / (1.0f + ex);
        float w1 = ex / (1.0f + ex);
        int p0 = atomicAdd(&cnt[e0], 1);
        int p1 = atomicAdd(&cnt[e1], 1);
        route_i[n] = make_int4(e0, e1, p0, p1);
        route_w[n] = make_float2(w0, w1);
    }
}

// ---- scan: 128-aligned per-expert segment bases ------------------------
__global__ void k_scan(const int* __restrict__ cnt, int* __restrict__ base) {
    if (threadIdx.x == 0) {
        int pb = 0;
        for (int e = 0; e < NEXP; e++) { base[e] = pb; pb += ((cnt[e] + 127) >> 7) << 7; }
        base[NEXP] = pb;
    }
}

// ---- pack: x fp32 -> bf16 rows packed per expert segment ---------------
__global__ __launch_bounds__(256) void k_pack(
    const float* __restrict__ x, const int* __restrict__ base,
    const int4* __restrict__ route_i, const float2* __restrict__ route_w,
    u16* __restrict__ Xp, int* __restrict__ tok_idx, float* __restrict__ tok_w) {
    int n = blockIdx.x, tid = threadIdx.x;
    int4 ri = route_i[n]; float2 rw = route_w[n];
    size_t r0 = (size_t)base[ri.x] + ri.z;
    size_t r1 = (size_t)base[ri.y] + ri.w;
    const float4* xr = (const float4*)(x + (size_t)n * DIM) + tid * 2;
    float4 a = xr[0], b = xr[1];
    uint4 o;
    o.x = (unsigned)f2bf(a.x) | ((unsigned)f2bf(a.y) << 16);
    o.y = (unsigned)f2bf(a.z) | ((unsigned)f2bf(a.w) << 16);
    o.z = (unsigned)f2bf(b.x) | ((unsigned)f2bf(b.y) << 16);
    o.w = (unsigned)f2bf(b.z) | ((unsigned)f2bf(b.w) << 16);
    ((uint4*)(Xp + r0 * DIM))[tid] = o;
    ((uint4*)(Xp + r1 * DIM))[tid] = o;
    if (tid == 0) {
        tok_idx[r0] = n; tok_w[r0] = rw.x;
        tok_idx[r1] = n; tok_w[r1] = rw.y;
    }
}

// ---- transpose We[e][k][n] fp32 -> Wt[e][n][k] bf16, vectorized --------
__global__ void k_transpose_we(const float* __restrict__ We, u16* __restrict__ Wt) {
    __shared__ float t[64][65];
    int e = blockIdx.z, k0 = blockIdx.y * 64, n0 = blockIdx.x * 64;
    const float* src = We + ((size_t)e * DIM + k0) * DIM + n0;
    int tid = threadIdx.x;
#pragma unroll
    for (int it = 0; it < 4; it++) {
        int item = it * 256 + tid;            // 1024 float4 loads
        int r = item >> 4, c4 = (item & 15) * 4;
        float4 v = *(const float4*)(src + (size_t)r * DIM + c4);
        t[r][c4] = v.x; t[r][c4 + 1] = v.y; t[r][c4 + 2] = v.z; t[r][c4 + 3] = v.w;
    }
    __syncthreads();
    u16* dst = Wt + ((size_t)e * DIM + n0) * DIM + k0;
#pragma unroll
    for (int it = 0; it < 2; it++) {
        int item = it * 256 + tid;            // 512 uint4 stores
        int nl = item >> 3, kc = (item & 7) * 8;
        unsigned m[8];
#pragma unroll
        for (int j = 0; j < 8; j++) m[j] = f2bf(t[kc + j][nl]);
        uint4 o;
        o.x = m[0] | (m[1] << 16); o.y = m[2] | (m[3] << 16);
        o.z = m[4] | (m[5] << 16); o.w = m[6] | (m[7] << 16);
        *(uint4*)(dst + (size_t)nl * DIM + kc) = o;
    }
}

// ---- grouped dense GEMM + scaled scatter-add ---------------------------
// BM=128, BN=128, BK=32; 4 waves, 64x64 subtile each (4x4 mfma 16x16x32)
__global__ __launch_bounds__(256) void k_moe_gemm(
    const u16* __restrict__ Xp, const u16* __restrict__ Wt,
    const float* __restrict__ be, const int* __restrict__ cnt,
    const int* __restrict__ base, const int* __restrict__ tok_idx,
    const float* __restrict__ tok_w, float* __restrict__ out) {
    int m0 = blockIdx.y * 128;
    if (m0 >= base[NEXP]) return;
    int e = 0;
#pragma unroll
    for (int i = 1; i < NEXP; i++) if (m0 >= base[i]) e = i;
    int limit = base[e] + cnt[e];
    int n0 = blockIdx.x * 128;

    __shared__ u16 As[128 * 32];
    __shared__ u16 Bs[128 * 32];

    int tid = threadIdx.x;
    int wave = tid >> 6, lane = tid & 63;

    // staging: each wave stages 16 rows/round; XOR-swizzle the 16B chunk
    // on the GLOBAL side so LDS dest stays lane-ordered contiguous.
    int srow = wave * 16 + (lane >> 2);
    int scol = ((lane & 3) ^ ((srow >> 1) & 3)) * 8;   // (srow+64) has same swizzle
    const u16* gA0 = Xp + (size_t)(m0 + srow) * DIM + scol;
    const u16* gA1 = gA0 + (size_t)64 * DIM;
    const u16* gB0 = Wt + ((size_t)e * DIM + n0 + srow) * DIM + scol;
    const u16* gB1 = gB0 + (size_t)64 * DIM;
    u16* lA0 = As + (wave * 16) * 32;
    u16* lA1 = As + (64 + wave * 16) * 32;
    u16* lB0 = Bs + (wave * 16) * 32;
    u16* lB1 = Bs + (64 + wave * 16) * 32;

    int wr = (wave >> 1) * 64, wc = (wave & 1) * 64;
    int q = lane >> 4, mr = lane & 15;

    f32x4 acc[4][4] = {};

    for (int kk = 0; kk < DIM; kk += 32) {
        gload16(gA0 + kk, lA0);
        gload16(gA1 + kk, lA1);
        gload16(gB0 + kk, lB0);
        gload16(gB1 + kk, lB1);
        __syncthreads();
        bf16x8 af[4], bfr[4];
#pragma unroll
        for (int i = 0; i < 4; i++) {
            int R = wr + i * 16 + mr;
            af[i] = *(const bf16x8*)(As + R * 32 + (q ^ ((R >> 1) & 3)) * 8);
        }
#pragma unroll
        for (int j = 0; j < 4; j++) {
            int R = wc + j * 16 + mr;
            bfr[j] = *(const bf16x8*)(Bs + R * 32 + (q ^ ((R >> 1) & 3)) * 8);
        }
#pragma unroll
        for (int i = 0; i < 4; i++)
#pragma unroll
            for (int j = 0; j < 4; j++)
                acc[i][j] = __builtin_amdgcn_mfma_f32_16x16x32_bf16(
                    af[i], bfr[j], acc[i][j], 0, 0, 0);
        __syncthreads();
    }

    // epilogue: C/D layout col=lane&15, row=(lane>>4)*4+reg
    float bev[4];
#pragma unroll
    for (int j = 0; j < 4; j++) bev[j] = be[e * DIM + n0 + wc + j * 16 + mr];
#pragma unroll
    for (int i = 0; i < 4; i++) {
#pragma unroll
        for (int r = 0; r < 4; r++) {
            int gr = m0 + wr + i * 16 + q * 4 + r;
            if (gr < limit) {
                int t = tok_idx[gr];
                float w = tok_w[gr];
                float* orow = out + (size_t)t * DIM + n0 + wc + mr;
#pragma unroll
                for (int j = 0; j < 4; j++)
                    atomicAdd(orow + j * 16, w * (acc[i][j][r] + bev[j]));
            }
        }
    }
}

extern "C" void kernel_launch(void* const* d_in, const int* in_sizes, int n_in,
                              void* d_out, int out_size, void* d_ws, size_t ws_size,
                              hipStream_t stream) {
    const float* x  = (const float*)d_in[0];   // [N, D]
    const float* Wg = (const float*)d_in[1];   // [D, E]
    const float* We = (const float*)d_in[2];   // [E, D, D]
    const float* be = (const float*)d_in[3];   // [E, D]
    float* out = (float*)d_out;                // [N, D] fp32
    char* ws = (char*)d_ws;
    int*    cnt     = (int*)(ws + OFF_CNT);
    int*    base    = (int*)(ws + OFF_BASE);
    int4*   route_i = (int4*)(ws + OFF_RI);
    float2* route_w = (float2*)(ws + OFF_RW);
    int*    tok_idx = (int*)(ws + OFF_TIDX);
    float*  tok_w   = (float*)(ws + OFF_TW);
    u16*    Xp      = (u16*)(ws + OFF_XP);
    u16*    Wt      = (u16*)(ws + OFF_WT);

    hipMemsetAsync(cnt, 0, 512, stream);
    hipMemsetAsync(out, 0, (size_t)N_TOK * DIM * 4, stream);
    k_gate<<<N_TOK / 4, 256, 0, stream>>>(x, Wg, cnt, route_i, route_w);
    k_scan<<<1, 64, 0, stream>>>(cnt, base);
    k_transpose_we<<<dim3(DIM / 64, DIM / 64, NEXP), 256, 0, stream>>>(We, Wt);
    k_pack<<<N_TOK, 256, 0, stream>>>(x, base, route_i, route_w, Xp, tok_idx, tok_w);
    k_moe_gemm<<<dim3(DIM / 128, RPAD / 128, 1), 256, 0, stream>>>(
        Xp, Wt, be, cnt, base, tok_idx, tok_w, out);
}

// Round 3
// 663.166 us; speedup vs baseline: 1.1276x; 1.1235x over previous
//
#include <hip/hip_runtime.h>
#include <stdint.h>

typedef unsigned short u16;
typedef __bf16 bf16x8 __attribute__((ext_vector_type(8)));
typedef float  f32x4  __attribute__((ext_vector_type(4)));

#define N_TOK 8192
#define DIM   2048
#define NEXP  8
#define RPAD  17408   // 136*128 >= 2*N_TOK + 8*127, rounded to 128

// ---- ws layout (bytes) ----
#define OFF_CNT   0                               // int[8]
#define OFF_RI    256                             // int4[N_TOK]  (e0,e1,p0,p1)
#define OFF_RW    (OFF_RI + N_TOK * 16)           // float2[N_TOK]
#define OFF_TIDX  (OFF_RW + N_TOK * 8)            // int[NEXP*N_TOK]
#define OFF_XB    (OFF_TIDX + NEXP * N_TOK * 4)   // u16[N_TOK*DIM]
#define OFF_WT    (OFF_XB + (size_t)N_TOK * DIM * 2)   // u16[NEXP*DIM*DIM]
#define OFF_YP    (OFF_WT + (size_t)NEXP * DIM * DIM * 2)  // u16[RPAD*DIM]
// total = OFF_YP + RPAD*DIM*2 ~= 172.4 MB

__device__ __forceinline__ u16 f2bf(float f) {
    unsigned int u = __float_as_uint(f);
    u = (u + 0x7FFFu + ((u >> 16) & 1u)) >> 16;   // RNE; inputs finite
    return (u16)u;
}

__device__ __forceinline__ void gload16(const void* g, void* l) {
    __builtin_amdgcn_global_load_lds(
        (const __attribute__((address_space(1))) unsigned int*)g,
        (__attribute__((address_space(3))) unsigned int*)l,
        16, 0, 0);
}

// ---- gate: bf16-convert row, fp64 logits, top-2, expert lists ----------
__global__ void k_gate(const float* __restrict__ x, const float* __restrict__ Wg,
                       int* __restrict__ cnt, int* __restrict__ tok_idx,
                       int4* __restrict__ route_i, float2* __restrict__ route_w,
                       u16* __restrict__ Xb) {
    int wave = threadIdx.x >> 6, lane = threadIdx.x & 63;
    int n = blockIdx.x * 4 + wave;
    const float* xr = x + (size_t)n * DIM;
    u16* xbr = Xb + (size_t)n * DIM;
#pragma unroll
    for (int it = 0; it < 4; it++) {
        int c = (it * 64 + lane) * 8;
        float4 a = *(const float4*)(xr + c), b = *(const float4*)(xr + c + 4);
        uint4 o;
        o.x = (unsigned)f2bf(a.x) | ((unsigned)f2bf(a.y) << 16);
        o.y = (unsigned)f2bf(a.z) | ((unsigned)f2bf(a.w) << 16);
        o.z = (unsigned)f2bf(b.x) | ((unsigned)f2bf(b.y) << 16);
        o.w = (unsigned)f2bf(b.z) | ((unsigned)f2bf(b.w) << 16);
        *(uint4*)(xbr + c) = o;
    }
    double acc[8] = {0, 0, 0, 0, 0, 0, 0, 0};
    for (int d = lane; d < DIM; d += 64) {
        float xv = xr[d];
        const float4* wg = (const float4*)(Wg + d * 8);
        float4 w0 = wg[0], w1 = wg[1];
        acc[0] += (double)xv * (double)w0.x;
        acc[1] += (double)xv * (double)w0.y;
        acc[2] += (double)xv * (double)w0.z;
        acc[3] += (double)xv * (double)w0.w;
        acc[4] += (double)xv * (double)w1.x;
        acc[5] += (double)xv * (double)w1.y;
        acc[6] += (double)xv * (double)w1.z;
        acc[7] += (double)xv * (double)w1.w;
    }
#pragma unroll
    for (int off = 32; off; off >>= 1)
#pragma unroll
        for (int e = 0; e < 8; e++) acc[e] += __shfl_xor(acc[e], off);
    if (lane == 0) {
        float v[8];
#pragma unroll
        for (int e = 0; e < 8; e++) v[e] = (float)acc[e];
        int e0 = 0; float v0 = v[0];
#pragma unroll
        for (int e = 1; e < 8; e++) if (v[e] > v0) { v0 = v[e]; e0 = e; }
        int e1 = -1; float v1 = -1e30f;
#pragma unroll
        for (int e = 0; e < 8; e++) if (e != e0 && v[e] > v1) { v1 = v[e]; e1 = e; }
        float ex = expf(v1 - v0);             // <= 1, stable
        float w0 = 1.0f / (1.0f + ex);
        float w1 = ex / (1.0f + ex);
        int p0 = atomicAdd(&cnt[e0], 1);
        int p1 = atomicAdd(&cnt[e1], 1);
        tok_idx[e0 * N_TOK + p0] = n;
        tok_idx[e1 * N_TOK + p1] = n;
        route_i[n] = make_int4(e0, e1, p0, p1);
        route_w[n] = make_float2(w0, w1);
    }
}

// ---- transpose We[e][k][n] fp32 -> Wt[e][n][k] bf16 --------------------
__global__ void k_transpose_we(const float* __restrict__ We, u16* __restrict__ Wt) {
    __shared__ float t[64][65];
    int e = blockIdx.z, k0 = blockIdx.y * 64, n0 = blockIdx.x * 64;
    const float* src = We + ((size_t)e * DIM + k0) * DIM + n0;
    int tid = threadIdx.x;
#pragma unroll
    for (int it = 0; it < 4; it++) {
        int item = it * 256 + tid;
        int r = item >> 4, c4 = (item & 15) * 4;
        float4 v = *(const float4*)(src + (size_t)r * DIM + c4);
        t[r][c4] = v.x; t[r][c4 + 1] = v.y; t[r][c4 + 2] = v.z; t[r][c4 + 3] = v.w;
    }
    __syncthreads();
    u16* dst = Wt + ((size_t)e * DIM + n0) * DIM + k0;
#pragma unroll
    for (int it = 0; it < 2; it++) {
        int item = it * 256 + tid;
        int nl = item >> 3, kc = (item & 7) * 8;
        unsigned m[8];
#pragma unroll
        for (int j = 0; j < 8; j++) m[j] = f2bf(t[kc + j][nl]);
        uint4 o;
        o.x = m[0] | (m[1] << 16); o.y = m[2] | (m[3] << 16);
        o.z = m[4] | (m[5] << 16); o.w = m[6] | (m[7] << 16);
        *(uint4*)(dst + (size_t)nl * DIM + kc) = o;
    }
}

// ---- grouped gather-GEMM, atomic-free: Y[row] = x_row @ We[e] + be -----
// BM=128, BN=128, BK=32; 4 waves, 64x64 subtile each (4x4 mfma 16x16x32)
__global__ __launch_bounds__(256) void k_moe_gemm(
    const u16* __restrict__ Xb, const u16* __restrict__ Wt,
    const float* __restrict__ be, const int* __restrict__ cnt,
    const int* __restrict__ tok_idx, u16* __restrict__ Yp) {
    int base[NEXP]; int pb = 0;
#pragma unroll
    for (int i = 0; i < NEXP; i++) { base[i] = pb; pb += ((cnt[i] + 127) >> 7) << 7; }
    int m0 = blockIdx.y * 128;
    if (m0 >= pb) return;
    int e = 0;
#pragma unroll
    for (int i = 1; i < NEXP; i++) if (m0 >= base[i]) e = i;
    int n0 = blockIdx.x * 128;

    __shared__ u16 As[128 * 32];
    __shared__ u16 Bs[128 * 32];

    int tid = threadIdx.x;
    int wave = tid >> 6, lane = tid & 63;

    // staging: 16 rows/wave/round; XOR-swizzle the 16B chunk on the GLOBAL
    // side so the LDS dest stays lane-ordered contiguous (m104 rule).
    int srow = wave * 16 + (lane >> 2);
    int scol = ((lane & 3) ^ ((srow >> 1) & 3)) * 8;   // srow+64: same swizzle
    int slot = m0 + srow - base[e];
    int t0 = tok_idx[e * N_TOK + slot] & (N_TOK - 1);        // pad rows: poison-masked
    int t1 = tok_idx[e * N_TOK + slot + 64] & (N_TOK - 1);
    const u16* gA0 = Xb + (size_t)t0 * DIM + scol;
    const u16* gA1 = Xb + (size_t)t1 * DIM + scol;
    const u16* gB0 = Wt + ((size_t)e * DIM + n0 + srow) * DIM + scol;
    const u16* gB1 = gB0 + (size_t)64 * DIM;
    u16* lA0 = As + (wave * 16) * 32;
    u16* lA1 = As + (64 + wave * 16) * 32;
    u16* lB0 = Bs + (wave * 16) * 32;
    u16* lB1 = Bs + (64 + wave * 16) * 32;

    int wr = (wave >> 1) * 64, wc = (wave & 1) * 64;
    int q = lane >> 4, mr = lane & 15;

    f32x4 acc[4][4] = {};

    for (int kk = 0; kk < DIM; kk += 32) {
        gload16(gA0 + kk, lA0);
        gload16(gA1 + kk, lA1);
        gload16(gB0 + kk, lB0);
        gload16(gB1 + kk, lB1);
        __syncthreads();
        bf16x8 af[4], bfr[4];
#pragma unroll
        for (int i = 0; i < 4; i++) {
            int R = wr + i * 16 + mr;
            af[i] = *(const bf16x8*)(As + R * 32 + (q ^ ((R >> 1) & 3)) * 8);
        }
#pragma unroll
        for (int j = 0; j < 4; j++) {
            int R = wc + j * 16 + mr;
            bfr[j] = *(const bf16x8*)(Bs + R * 32 + (q ^ ((R >> 1) & 3)) * 8);
        }
#pragma unroll
        for (int i = 0; i < 4; i++)
#pragma unroll
            for (int j = 0; j < 4; j++)
                acc[i][j] = __builtin_amdgcn_mfma_f32_16x16x32_bf16(
                    af[i], bfr[j], acc[i][j], 0, 0, 0);
        __syncthreads();
    }

    // epilogue: C/D layout col=lane&15, row=(lane>>4)*4+reg; plain bf16 stores
    float bev[4];
#pragma unroll
    for (int j = 0; j < 4; j++) bev[j] = be[e * DIM + n0 + wc + j * 16 + mr];
#pragma unroll
    for (int i = 0; i < 4; i++) {
#pragma unroll
        for (int r = 0; r < 4; r++) {
            int row = wr + i * 16 + q * 4 + r;
            u16* yrow = Yp + (size_t)(m0 + row) * DIM + n0 + wc + mr;
#pragma unroll
            for (int j = 0; j < 4; j++)
                yrow[j * 16] = f2bf(acc[i][j][r] + bev[j]);
        }
    }
}

// ---- combine: out[n] = w0*Y[r0] + w1*Y[r1] -----------------------------
__global__ __launch_bounds__(256) void k_combine(
    const u16* __restrict__ Yp, const int* __restrict__ cnt,
    const int4* __restrict__ route_i, const float2* __restrict__ route_w,
    float* __restrict__ out) {
    int base[NEXP]; int pb = 0;
#pragma unroll
    for (int i = 0; i < NEXP; i++) { base[i] = pb; pb += ((cnt[i] + 127) >> 7) << 7; }
    int n = blockIdx.x, tid = threadIdx.x;
    int4 ri = route_i[n]; float2 w = route_w[n];
    size_t r0 = (size_t)base[ri.x] + ri.z;
    size_t r1 = (size_t)base[ri.y] + ri.w;
    uint4 ya = ((const uint4*)(Yp + r0 * DIM))[tid];
    uint4 yb = ((const uint4*)(Yp + r1 * DIM))[tid];
    float4 o0, o1;
    unsigned a, b;
    a = ya.x; b = yb.x;
    o0.x = w.x * __uint_as_float(a << 16) + w.y * __uint_as_float(b << 16);
    o0.y = w.x * __uint_as_float(a & 0xffff0000u) + w.y * __uint_as_float(b & 0xffff0000u);
    a = ya.y; b = yb.y;
    o0.z = w.x * __uint_as_float(a << 16) + w.y * __uint_as_float(b << 16);
    o0.w = w.x * __uint_as_float(a & 0xffff0000u) + w.y * __uint_as_float(b & 0xffff0000u);
    a = ya.z; b = yb.z;
    o1.x = w.x * __uint_as_float(a << 16) + w.y * __uint_as_float(b << 16);
    o1.y = w.x * __uint_as_float(a & 0xffff0000u) + w.y * __uint_as_float(b & 0xffff0000u);
    a = ya.w; b = yb.w;
    o1.z = w.x * __uint_as_float(a << 16) + w.y * __uint_as_float(b << 16);
    o1.w = w.x * __uint_as_float(a & 0xffff0000u) + w.y * __uint_as_float(b & 0xffff0000u);
    float4* op = (float4*)(out + (size_t)n * DIM) + tid * 2;
    op[0] = o0; op[1] = o1;
}

extern "C" void kernel_launch(void* const* d_in, const int* in_sizes, int n_in,
                              void* d_out, int out_size, void* d_ws, size_t ws_size,
                              hipStream_t stream) {
    const float* x  = (const float*)d_in[0];   // [N, D]
    const float* Wg = (const float*)d_in[1];   // [D, E]
    const float* We = (const float*)d_in[2];   // [E, D, D]
    const float* be = (const float*)d_in[3];   // [E, D]
    float* out = (float*)d_out;                // [N, D] fp32
    char* ws = (char*)d_ws;
    int*    cnt     = (int*)(ws + OFF_CNT);
    int4*   route_i = (int4*)(ws + OFF_RI);
    float2* route_w = (float2*)(ws + OFF_RW);
    int*    tok_idx = (int*)(ws + OFF_TIDX);
    u16*    Xb      = (u16*)(ws + OFF_XB);
    u16*    Wt      = (u16*)(ws + OFF_WT);
    u16*    Yp      = (u16*)(ws + OFF_YP);

    hipMemsetAsync(cnt, 0, 256, stream);
    k_gate<<<N_TOK / 4, 256, 0, stream>>>(x, Wg, cnt, tok_idx, route_i, route_w, Xb);
    k_transpose_we<<<dim3(DIM / 64, DIM / 64, NEXP), 256, 0, stream>>>(We, Wt);
    k_moe_gemm<<<dim3(DIM / 128, RPAD / 128, 1), 256, 0, stream>>>(
        Xb, Wt, be, cnt, tok_idx, Yp);
    k_combine<<<N_TOK, 256, 0, stream>>>(Yp, cnt, route_i, route_w, out);
}

// Round 4
// 540.719 us; speedup vs baseline: 1.3829x; 1.2265x over previous
//
#include <hip/hip_runtime.h>
#include <stdint.h>

typedef unsigned short u16;
typedef __bf16 bf16x8 __attribute__((ext_vector_type(8)));
typedef float  f32x4  __attribute__((ext_vector_type(4)));

#define N_TOK 8192
#define DIM   2048
#define NEXP  8
#define RPAD  17408   // 136*128 >= 2*N_TOK + 8*127, rounded to 128

// ---- ws layout (bytes) ----
#define OFF_CNT   0                               // int[8]
#define OFF_RE    256                             // int2[N_TOK]  (e0,e1)
#define OFF_RI    (OFF_RE + N_TOK * 8)            // int4[N_TOK]  (e0,e1,p0,p1)
#define OFF_RW    (OFF_RI + N_TOK * 16)           // float2[N_TOK]
#define OFF_TIDX  (OFF_RW + N_TOK * 8)            // int[NEXP*N_TOK]
#define OFF_XB    (OFF_TIDX + NEXP * N_TOK * 4)   // u16[N_TOK*DIM]
#define OFF_WT    (OFF_XB + (size_t)N_TOK * DIM * 2)       // u16[NEXP*DIM*DIM]
#define OFF_YP    (OFF_WT + (size_t)NEXP * DIM * DIM * 2)  // u16[RPAD*DIM]
// total ~172.5 MB

__device__ __forceinline__ unsigned f2bf(float f) {
    unsigned int u = __float_as_uint(f);
    u = (u + 0x7FFFu + ((u >> 16) & 1u)) >> 16;   // RNE; inputs finite
    return u;
}

__device__ __forceinline__ void gload16(const void* g, void* l) {
    __builtin_amdgcn_global_load_lds(
        (const __attribute__((address_space(1))) unsigned int*)g,
        (__attribute__((address_space(3))) unsigned int*)l,
        16, 0, 0);
}

// ---- gate: fused convert + fp64 logits, top-2. NO atomics. -------------
__global__ __launch_bounds__(256) void k_gate(
    const float* __restrict__ x, const float* __restrict__ Wg,
    int2* __restrict__ route_e, float2* __restrict__ route_w,
    u16* __restrict__ Xb) {
    int wave = threadIdx.x >> 6, lane = threadIdx.x & 63;
    int n = blockIdx.x * 4 + wave;
    const float* xr = x + (size_t)n * DIM;
    u16* xbr = Xb + (size_t)n * DIM;
    double acc[8] = {0, 0, 0, 0, 0, 0, 0, 0};
#pragma unroll
    for (int it = 0; it < 4; it++) {
        int c = it * 512 + lane * 8;
        float4 a = *(const float4*)(xr + c);
        float4 b = *(const float4*)(xr + c + 4);
        uint4 o;
        o.x = f2bf(a.x) | (f2bf(a.y) << 16);
        o.y = f2bf(a.z) | (f2bf(a.w) << 16);
        o.z = f2bf(b.x) | (f2bf(b.y) << 16);
        o.w = f2bf(b.z) | (f2bf(b.w) << 16);
        *(uint4*)(xbr + c) = o;
        float xv[8] = {a.x, a.y, a.z, a.w, b.x, b.y, b.z, b.w};
        const float4* wp = (const float4*)(Wg + (size_t)c * 8);
#pragma unroll
        for (int j = 0; j < 8; j++) {
            float4 w0 = wp[j * 2], w1 = wp[j * 2 + 1];
            double xd = (double)xv[j];
            acc[0] += xd * (double)w0.x;
            acc[1] += xd * (double)w0.y;
            acc[2] += xd * (double)w0.z;
            acc[3] += xd * (double)w0.w;
            acc[4] += xd * (double)w1.x;
            acc[5] += xd * (double)w1.y;
            acc[6] += xd * (double)w1.z;
            acc[7] += xd * (double)w1.w;
        }
    }
#pragma unroll
    for (int off = 32; off; off >>= 1)
#pragma unroll
        for (int e = 0; e < 8; e++) acc[e] += __shfl_xor(acc[e], off);
    if (lane == 0) {
        float v[8];
#pragma unroll
        for (int e = 0; e < 8; e++) v[e] = (float)acc[e];
        int e0 = 0; float v0 = v[0];
#pragma unroll
        for (int e = 1; e < 8; e++) if (v[e] > v0) { v0 = v[e]; e0 = e; }
        int e1 = -1; float v1 = -1e30f;
#pragma unroll
        for (int e = 0; e < 8; e++) if (e != e0 && v[e] > v1) { v1 = v[e]; e1 = e; }
        float ex = expf(v1 - v0);             // <= 1, stable
        route_e[n] = make_int2(e0, e1);
        route_w[n] = make_float2(1.0f / (1.0f + ex), ex / (1.0f + ex));
    }
}

// ---- slots: deterministic slot assignment, one block -------------------
__global__ __launch_bounds__(256) void k_slots(
    const int2* __restrict__ route_e, int4* __restrict__ route_i,
    int* __restrict__ cnt, int* __restrict__ tok_idx) {
    __shared__ int lc[256][NEXP];
    int t = threadIdx.x;
#pragma unroll
    for (int e = 0; e < NEXP; e++) lc[t][e] = 0;
    int2 re[32];
#pragma unroll 4
    for (int i = 0; i < 32; i++) {
        re[i] = route_e[t * 32 + i];
        lc[t][re[i].x]++;
        lc[t][re[i].y]++;
    }
    __syncthreads();
    if (t < NEXP) {          // exclusive scan per expert (serial, 256 steps)
        int run = 0;
        for (int b = 0; b < 256; b++) { int v = lc[b][t]; lc[b][t] = run; run += v; }
        cnt[t] = run;
    }
    __syncthreads();
#pragma unroll 4
    for (int i = 0; i < 32; i++) {
        int n = t * 32 + i;
        int p0 = lc[t][re[i].x]++;
        int p1 = lc[t][re[i].y]++;
        route_i[n] = make_int4(re[i].x, re[i].y, p0, p1);
        tok_idx[re[i].x * N_TOK + p0] = n;
        tok_idx[re[i].y * N_TOK + p1] = n;
    }
}

// ---- transpose We[e][k][n] fp32 -> Wt[e][n][k] bf16 --------------------
__global__ void k_transpose_we(const float* __restrict__ We, u16* __restrict__ Wt) {
    __shared__ float t[64][65];
    int e = blockIdx.z, k0 = blockIdx.y * 64, n0 = blockIdx.x * 64;
    const float* src = We + ((size_t)e * DIM + k0) * DIM + n0;
    int tid = threadIdx.x;
#pragma unroll
    for (int it = 0; it < 4; it++) {
        int item = it * 256 + tid;
        int r = item >> 4, c4 = (item & 15) * 4;
        float4 v = *(const float4*)(src + (size_t)r * DIM + c4);
        t[r][c4] = v.x; t[r][c4 + 1] = v.y; t[r][c4 + 2] = v.z; t[r][c4 + 3] = v.w;
    }
    __syncthreads();
    u16* dst = Wt + ((size_t)e * DIM + n0) * DIM + k0;
#pragma unroll
    for (int it = 0; it < 2; it++) {
        int item = it * 256 + tid;
        int nl = item >> 3, kc = (item & 7) * 8;
        unsigned m[8];
#pragma unroll
        for (int j = 0; j < 8; j++) m[j] = f2bf(t[kc + j][nl]);
        uint4 o;
        o.x = m[0] | (m[1] << 16); o.y = m[2] | (m[3] << 16);
        o.z = m[4] | (m[5] << 16); o.w = m[6] | (m[7] << 16);
        *(uint4*)(dst + (size_t)nl * DIM + kc) = o;
    }
}

// ---- grouped gather-GEMM, atomic-free: Y[row] = x_row @ We[e] + be -----
// BM=128, BN=128, BK=32; 4 waves, 64x64 subtile each (4x4 mfma 16x16x32)
__global__ __launch_bounds__(256) void k_moe_gemm(
    const u16* __restrict__ Xb, const u16* __restrict__ Wt,
    const float* __restrict__ be, const int* __restrict__ cnt,
    const int* __restrict__ tok_idx, u16* __restrict__ Yp) {
    int base[NEXP]; int pb = 0;
#pragma unroll
    for (int i = 0; i < NEXP; i++) { base[i] = pb; pb += ((cnt[i] + 127) >> 7) << 7; }
    int m0 = blockIdx.y * 128;
    if (m0 >= pb) return;
    int e = 0;
#pragma unroll
    for (int i = 1; i < NEXP; i++) if (m0 >= base[i]) e = i;
    int n0 = blockIdx.x * 128;

    __shared__ u16 As[128 * 32];
    __shared__ u16 Bs[128 * 32];

    int tid = threadIdx.x;
    int wave = tid >> 6, lane = tid & 63;

    int srow = wave * 16 + (lane >> 2);
    int scol = ((lane & 3) ^ ((srow >> 1) & 3)) * 8;   // global-side swizzle
    int slot = m0 + srow - base[e];
    int t0 = tok_idx[e * N_TOK + slot] & (N_TOK - 1);        // pad rows masked
    int t1 = tok_idx[e * N_TOK + slot + 64] & (N_TOK - 1);
    const u16* gA0 = Xb + (size_t)t0 * DIM + scol;
    const u16* gA1 = Xb + (size_t)t1 * DIM + scol;
    const u16* gB0 = Wt + ((size_t)e * DIM + n0 + srow) * DIM + scol;
    const u16* gB1 = gB0 + (size_t)64 * DIM;
    u16* lA0 = As + (wave * 16) * 32;
    u16* lA1 = As + (64 + wave * 16) * 32;
    u16* lB0 = Bs + (wave * 16) * 32;
    u16* lB1 = Bs + (64 + wave * 16) * 32;

    int wr = (wave >> 1) * 64, wc = (wave & 1) * 64;
    int q = lane >> 4, mr = lane & 15;

    f32x4 acc[4][4] = {};

    for (int kk = 0; kk < DIM; kk += 32) {
        gload16(gA0 + kk, lA0);
        gload16(gA1 + kk, lA1);
        gload16(gB0 + kk, lB0);
        gload16(gB1 + kk, lB1);
        __syncthreads();
        bf16x8 af[4], bfr[4];
#pragma unroll
        for (int i = 0; i < 4; i++) {
            int R = wr + i * 16 + mr;
            af[i] = *(const bf16x8*)(As + R * 32 + (q ^ ((R >> 1) & 3)) * 8);
        }
#pragma unroll
        for (int j = 0; j < 4; j++) {
            int R = wc + j * 16 + mr;
            bfr[j] = *(const bf16x8*)(Bs + R * 32 + (q ^ ((R >> 1) & 3)) * 8);
        }
#pragma unroll
        for (int i = 0; i < 4; i++)
#pragma unroll
            for (int j = 0; j < 4; j++)
                acc[i][j] = __builtin_amdgcn_mfma_f32_16x16x32_bf16(
                    af[i], bfr[j], acc[i][j], 0, 0, 0);
        __syncthreads();
    }

    float bev[4];
#pragma unroll
    for (int j = 0; j < 4; j++) bev[j] = be[e * DIM + n0 + wc + j * 16 + mr];
#pragma unroll
    for (int i = 0; i < 4; i++) {
#pragma unroll
        for (int r = 0; r < 4; r++) {
            int row = wr + i * 16 + q * 4 + r;
            u16* yrow = Yp + (size_t)(m0 + row) * DIM + n0 + wc + mr;
#pragma unroll
            for (int j = 0; j < 4; j++)
                yrow[j * 16] = (u16)f2bf(acc[i][j][r] + bev[j]);
        }
    }
}

// ---- combine: out[n] = w0*Y[r0] + w1*Y[r1] -----------------------------
__global__ __launch_bounds__(256) void k_combine(
    const u16* __restrict__ Yp, const int* __restrict__ cnt,
    const int4* __restrict__ route_i, const float2* __restrict__ route_w,
    float* __restrict__ out) {
    int base[NEXP]; int pb = 0;
#pragma unroll
    for (int i = 0; i < NEXP; i++) { base[i] = pb; pb += ((cnt[i] + 127) >> 7) << 7; }
    int n = blockIdx.x, tid = threadIdx.x;
    int4 ri = route_i[n]; float2 w = route_w[n];
    size_t r0 = (size_t)base[ri.x] + ri.z;
    size_t r1 = (size_t)base[ri.y] + ri.w;
    uint4 ya = ((const uint4*)(Yp + r0 * DIM))[tid];
    uint4 yb = ((const uint4*)(Yp + r1 * DIM))[tid];
    float4 o0, o1;
    unsigned a, b;
    a = ya.x; b = yb.x;
    o0.x = w.x * __uint_as_float(a << 16) + w.y * __uint_as_float(b << 16);
    o0.y = w.x * __uint_as_float(a & 0xffff0000u) + w.y * __uint_as_float(b & 0xffff0000u);
    a = ya.y; b = yb.y;
    o0.z = w.x * __uint_as_float(a << 16) + w.y * __uint_as_float(b << 16);
    o0.w = w.x * __uint_as_float(a & 0xffff0000u) + w.y * __uint_as_float(b & 0xffff0000u);
    a = ya.z; b = yb.z;
    o1.x = w.x * __uint_as_float(a << 16) + w.y * __uint_as_float(b << 16);
    o1.y = w.x * __uint_as_float(a & 0xffff0000u) + w.y * __uint_as_float(b & 0xffff0000u);
    a = ya.w; b = yb.w;
    o1.z = w.x * __uint_as_float(a << 16) + w.y * __uint_as_float(b << 16);
    o1.w = w.x * __uint_as_float(a & 0xffff0000u) + w.y * __uint_as_float(b & 0xffff0000u);
    float4* op = (float4*)(out + (size_t)n * DIM) + tid * 2;
    op[0] = o0; op[1] = o1;
}

extern "C" void kernel_launch(void* const* d_in, const int* in_sizes, int n_in,
                              void* d_out, int out_size, void* d_ws, size_t ws_size,
                              hipStream_t stream) {
    const float* x  = (const float*)d_in[0];   // [N, D]
    const float* Wg = (const float*)d_in[1];   // [D, E]
    const float* We = (const float*)d_in[2];   // [E, D, D]
    const float* be = (const float*)d_in[3];   // [E, D]
    float* out = (float*)d_out;                // [N, D] fp32
    char* ws = (char*)d_ws;
    int*    cnt     = (int*)(ws + OFF_CNT);
    int2*   route_e = (int2*)(ws + OFF_RE);
    int4*   route_i = (int4*)(ws + OFF_RI);
    float2* route_w = (float2*)(ws + OFF_RW);
    int*    tok_idx = (int*)(ws + OFF_TIDX);
    u16*    Xb      = (u16*)(ws + OFF_XB);
    u16*    Wt      = (u16*)(ws + OFF_WT);
    u16*    Yp      = (u16*)(ws + OFF_YP);

    k_gate<<<N_TOK / 4, 256, 0, stream>>>(x, Wg, route_e, route_w, Xb);
    k_slots<<<1, 256, 0, stream>>>(route_e, route_i, cnt, tok_idx);
    k_transpose_we<<<dim3(DIM / 64, DIM / 64, NEXP), 256, 0, stream>>>(We, Wt);
    k_moe_gemm<<<dim3(DIM / 128, RPAD / 128, 1), 256, 0, stream>>>(
        Xb, Wt, be, cnt, tok_idx, Yp);
    k_combine<<<N_TOK, 256, 0, stream>>>(Yp, cnt, route_i, route_w, out);
}

// Round 5
// 515.261 us; speedup vs baseline: 1.4513x; 1.0494x over previous
//
#include <hip/hip_runtime.h>
#include <stdint.h>

typedef unsigned short u16;
typedef __bf16 bf16x8 __attribute__((ext_vector_type(8)));
typedef float  f32x4  __attribute__((ext_vector_type(4)));

#define N_TOK 8192
#define DIM   2048
#define NEXP  8
#define RPAD  17408   // >= 2*N_TOK + 8*127, rounded to 128
#define NCHUNK 32     // token chunks for slot assignment (256 tokens each)

// ---- ws layout (bytes) ----
#define OFF_CNT   0                       // int[8]
#define OFF_HIST  1024                    // int[NCHUNK*8]
#define OFF_PRE   2048                    // int[NCHUNK*8]
#define OFF_RE    4096                    // int2[N_TOK]
#define OFF_RI    (OFF_RE + N_TOK * 8)    // int4[N_TOK]
#define OFF_RW    (OFF_RI + N_TOK * 16)   // float2[N_TOK]
#define OFF_TIDX  (OFF_RW + N_TOK * 8)    // int[NEXP*N_TOK]
#define OFF_XB    (OFF_TIDX + NEXP * N_TOK * 4)            // u16[N_TOK*DIM]
#define OFF_WT    (OFF_XB + (size_t)N_TOK * DIM * 2)       // u16[NEXP*DIM*DIM]
#define OFF_YP    (OFF_WT + (size_t)NEXP * DIM * DIM * 2)  // u16[RPAD*DIM]
// total ~172.5 MB

__device__ __forceinline__ unsigned f2bf(float f) {
    unsigned int u = __float_as_uint(f);
    u = (u + 0x7FFFu + ((u >> 16) & 1u)) >> 16;   // RNE; inputs finite
    return u;
}

__device__ __forceinline__ void gload16(const void* g, void* l) {
    __builtin_amdgcn_global_load_lds(
        (const __attribute__((address_space(1))) unsigned int*)g,
        (__attribute__((address_space(3))) unsigned int*)l,
        16, 0, 0);
}

// ---- gate: fused convert + fp64 logits, top-2. NO atomics. -------------
__global__ __launch_bounds__(256) void k_gate(
    const float* __restrict__ x, const float* __restrict__ Wg,
    int2* __restrict__ route_e, float2* __restrict__ route_w,
    u16* __restrict__ Xb) {
    int wave = threadIdx.x >> 6, lane = threadIdx.x & 63;
    int n = blockIdx.x * 4 + wave;
    const float* xr = x + (size_t)n * DIM;
    u16* xbr = Xb + (size_t)n * DIM;
    double acc[8] = {0, 0, 0, 0, 0, 0, 0, 0};
#pragma unroll
    for (int it = 0; it < 4; it++) {
        int c = it * 512 + lane * 8;
        float4 a = *(const float4*)(xr + c);
        float4 b = *(const float4*)(xr + c + 4);
        uint4 o;
        o.x = f2bf(a.x) | (f2bf(a.y) << 16);
        o.y = f2bf(a.z) | (f2bf(a.w) << 16);
        o.z = f2bf(b.x) | (f2bf(b.y) << 16);
        o.w = f2bf(b.z) | (f2bf(b.w) << 16);
        *(uint4*)(xbr + c) = o;
        float xv[8] = {a.x, a.y, a.z, a.w, b.x, b.y, b.z, b.w};
        const float4* wp = (const float4*)(Wg + (size_t)c * 8);
#pragma unroll
        for (int j = 0; j < 8; j++) {
            float4 w0 = wp[j * 2], w1 = wp[j * 2 + 1];
            double xd = (double)xv[j];
            acc[0] += xd * (double)w0.x;
            acc[1] += xd * (double)w0.y;
            acc[2] += xd * (double)w0.z;
            acc[3] += xd * (double)w0.w;
            acc[4] += xd * (double)w1.x;
            acc[5] += xd * (double)w1.y;
            acc[6] += xd * (double)w1.z;
            acc[7] += xd * (double)w1.w;
        }
    }
#pragma unroll
    for (int off = 32; off; off >>= 1)
#pragma unroll
        for (int e = 0; e < 8; e++) acc[e] += __shfl_xor(acc[e], off);
    if (lane == 0) {
        float v[8];
#pragma unroll
        for (int e = 0; e < 8; e++) v[e] = (float)acc[e];
        int e0 = 0; float v0 = v[0];
#pragma unroll
        for (int e = 1; e < 8; e++) if (v[e] > v0) { v0 = v[e]; e0 = e; }
        int e1 = -1; float v1 = -1e30f;
#pragma unroll
        for (int e = 0; e < 8; e++) if (e != e0 && v[e] > v1) { v1 = v[e]; e1 = e; }
        float ex = expf(v1 - v0);             // <= 1, stable
        route_e[n] = make_int2(e0, e1);
        route_w[n] = make_float2(1.0f / (1.0f + ex), ex / (1.0f + ex));
    }
}

// ---- hist: per-chunk expert histograms (32 blocks) ---------------------
__global__ __launch_bounds__(256) void k_hist(
    const int2* __restrict__ route_e, int* __restrict__ hist) {
    __shared__ int h[NEXP];
    int c = blockIdx.x, t = threadIdx.x;
    if (t < NEXP) h[t] = 0;
    __syncthreads();
    int2 re = route_e[c * 256 + t];
    atomicAdd(&h[re.x], 1);
    atomicAdd(&h[re.y], 1);
    __syncthreads();
    if (t < NEXP) hist[c * NEXP + t] = h[t];
}

// ---- scan: per-expert exclusive prefix over chunks (nano) --------------
__global__ void k_scan(const int* __restrict__ hist, int* __restrict__ pre,
                       int* __restrict__ cnt) {
    int e = threadIdx.x;
    if (e < NEXP) {
        int run = 0;
        for (int c = 0; c < NCHUNK; c++) { pre[c * NEXP + e] = run; run += hist[c * NEXP + e]; }
        cnt[e] = run;
    }
}

// ---- assign: ballot-ranked slot assignment (32 blocks) -----------------
__global__ __launch_bounds__(256) void k_assign(
    const int2* __restrict__ route_e, const int* __restrict__ pre,
    int4* __restrict__ route_i, int* __restrict__ tok_idx) {
    __shared__ int wc0[4][NEXP], wc1[4][NEXP];
    int c = blockIdx.x, t = threadIdx.x, wave = t >> 6, lane = t & 63;
    int n = c * 256 + t;
    int2 re = route_e[n];
    unsigned long long lt = ((unsigned long long)1 << lane) - 1;
    int r0 = 0, r1 = 0;
#pragma unroll
    for (int e = 0; e < NEXP; e++) {
        unsigned long long m0 = __ballot(re.x == e);
        unsigned long long m1 = __ballot(re.y == e);
        if (lane == 0) { wc0[wave][e] = __popcll(m0); wc1[wave][e] = __popcll(m1); }
        if (re.x == e) r0 = __popcll(m0 & lt);
        if (re.y == e) r1 = __popcll(m1 & lt);
    }
    __syncthreads();
    int h0tot = 0;   // total e0-instances of expert re.y in this chunk
#pragma unroll
    for (int w = 0; w < 4; w++) {
        if (w < wave) { r0 += wc0[w][re.x]; r1 += wc1[w][re.y]; }
        h0tot += wc0[w][re.y];
    }
    int p0 = pre[c * NEXP + re.x] + r0;
    int p1 = pre[c * NEXP + re.y] + h0tot + r1;
    route_i[n] = make_int4(re.x, re.y, p0, p1);
    tok_idx[re.x * N_TOK + p0] = n;
    tok_idx[re.y * N_TOK + p1] = n;
}

// ---- transpose We[e][k][n] fp32 -> Wt[e][n][k] bf16, 4 tiles/block -----
__global__ __launch_bounds__(256) void k_transpose_we(
    const float* __restrict__ We, u16* __restrict__ Wt) {
    __shared__ float t[64][65];
    int e = blockIdx.z, n0 = blockIdx.x * 64, k00 = blockIdx.y * 256;
    int tid = threadIdx.x;
    for (int kt = 0; kt < 4; kt++) {
        int k0 = k00 + kt * 64;
        const float* src = We + ((size_t)e * DIM + k0) * DIM + n0;
        if (kt) __syncthreads();
#pragma unroll
        for (int it = 0; it < 4; it++) {
            int item = it * 256 + tid;
            int r = item >> 4, c4 = (item & 15) * 4;
            float4 v = *(const float4*)(src + (size_t)r * DIM + c4);
            t[r][c4] = v.x; t[r][c4 + 1] = v.y; t[r][c4 + 2] = v.z; t[r][c4 + 3] = v.w;
        }
        __syncthreads();
        u16* dst = Wt + ((size_t)e * DIM + n0) * DIM + k0;
#pragma unroll
        for (int it = 0; it < 2; it++) {
            int item = it * 256 + tid;
            int nl = item >> 3, kc = (item & 7) * 8;
            unsigned m[8];
#pragma unroll
            for (int j = 0; j < 8; j++) m[j] = f2bf(t[kc + j][nl]);
            uint4 o;
            o.x = m[0] | (m[1] << 16); o.y = m[2] | (m[3] << 16);
            o.z = m[4] | (m[5] << 16); o.w = m[6] | (m[7] << 16);
            *(uint4*)(dst + (size_t)nl * DIM + kc) = o;
        }
    }
}

// ---- grouped gather-GEMM, atomic-free: Y[row] = x_row @ We[e] + be -----
__global__ __launch_bounds__(256) void k_moe_gemm(
    const u16* __restrict__ Xb, const u16* __restrict__ Wt,
    const float* __restrict__ be, const int* __restrict__ cnt,
    const int* __restrict__ tok_idx, u16* __restrict__ Yp) {
    int base[NEXP]; int pb = 0;
#pragma unroll
    for (int i = 0; i < NEXP; i++) { base[i] = pb; pb += ((cnt[i] + 127) >> 7) << 7; }
    int m0 = blockIdx.y * 128;
    if (m0 >= pb) return;
    int e = 0;
#pragma unroll
    for (int i = 1; i < NEXP; i++) if (m0 >= base[i]) e = i;
    int n0 = blockIdx.x * 128;

    __shared__ u16 As[128 * 32];
    __shared__ u16 Bs[128 * 32];

    int tid = threadIdx.x;
    int wave = tid >> 6, lane = tid & 63;

    int srow = wave * 16 + (lane >> 2);
    int scol = ((lane & 3) ^ ((srow >> 1) & 3)) * 8;   // global-side swizzle
    int slot = m0 + srow - base[e];
    int t0 = tok_idx[e * N_TOK + slot] & (N_TOK - 1);        // pad rows masked
    int t1 = tok_idx[e * N_TOK + slot + 64] & (N_TOK - 1);
    const u16* gA0 = Xb + (size_t)t0 * DIM + scol;
    const u16* gA1 = Xb + (size_t)t1 * DIM + scol;
    const u16* gB0 = Wt + ((size_t)e * DIM + n0 + srow) * DIM + scol;
    const u16* gB1 = gB0 + (size_t)64 * DIM;
    u16* lA0 = As + (wave * 16) * 32;
    u16* lA1 = As + (64 + wave * 16) * 32;
    u16* lB0 = Bs + (wave * 16) * 32;
    u16* lB1 = Bs + (64 + wave * 16) * 32;

    int wr = (wave >> 1) * 64, wc = (wave & 1) * 64;
    int q = lane >> 4, mr = lane & 15;

    f32x4 acc[4][4] = {};

    for (int kk = 0; kk < DIM; kk += 32) {
        gload16(gA0 + kk, lA0);
        gload16(gA1 + kk, lA1);
        gload16(gB0 + kk, lB0);
        gload16(gB1 + kk, lB1);
        __syncthreads();
        bf16x8 af[4], bfr[4];
#pragma unroll
        for (int i = 0; i < 4; i++) {
            int R = wr + i * 16 + mr;
            af[i] = *(const bf16x8*)(As + R * 32 + (q ^ ((R >> 1) & 3)) * 8);
        }
#pragma unroll
        for (int j = 0; j < 4; j++) {
            int R = wc + j * 16 + mr;
            bfr[j] = *(const bf16x8*)(Bs + R * 32 + (q ^ ((R >> 1) & 3)) * 8);
        }
#pragma unroll
        for (int i = 0; i < 4; i++)
#pragma unroll
            for (int j = 0; j < 4; j++)
                acc[i][j] = __builtin_amdgcn_mfma_f32_16x16x32_bf16(
                    af[i], bfr[j], acc[i][j], 0, 0, 0);
        __syncthreads();
    }

    float bev[4];
#pragma unroll
    for (int j = 0; j < 4; j++) bev[j] = be[e * DIM + n0 + wc + j * 16 + mr];
#pragma unroll
    for (int i = 0; i < 4; i++) {
#pragma unroll
        for (int r = 0; r < 4; r++) {
            int row = wr + i * 16 + q * 4 + r;
            u16* yrow = Yp + (size_t)(m0 + row) * DIM + n0 + wc + mr;
#pragma unroll
            for (int j = 0; j < 4; j++)
                yrow[j * 16] = (u16)f2bf(acc[i][j][r] + bev[j]);
        }
    }
}

// ---- combine: out[n] = w0*Y[r0] + w1*Y[r1] -----------------------------
__global__ __launch_bounds__(256) void k_combine(
    const u16* __restrict__ Yp, const int* __restrict__ cnt,
    const int4* __restrict__ route_i, const float2* __restrict__ route_w,
    float* __restrict__ out) {
    int base[NEXP]; int pb = 0;
#pragma unroll
    for (int i = 0; i < NEXP; i++) { base[i] = pb; pb += ((cnt[i] + 127) >> 7) << 7; }
    int n = blockIdx.x, tid = threadIdx.x;
    int4 ri = route_i[n]; float2 w = route_w[n];
    size_t r0 = (size_t)base[ri.x] + ri.z;
    size_t r1 = (size_t)base[ri.y] + ri.w;
    uint4 ya = ((const uint4*)(Yp + r0 * DIM))[tid];
    uint4 yb = ((const uint4*)(Yp + r1 * DIM))[tid];
    float4 o0, o1;
    unsigned a, b;
    a = ya.x; b = yb.x;
    o0.x = w.x * __uint_as_float(a << 16) + w.y * __uint_as_float(b << 16);
    o0.y = w.x * __uint_as_float(a & 0xffff0000u) + w.y * __uint_as_float(b & 0xffff0000u);
    a = ya.y; b = yb.y;
    o0.z = w.x * __uint_as_float(a << 16) + w.y * __uint_as_float(b << 16);
    o0.w = w.x * __uint_as_float(a & 0xffff0000u) + w.y * __uint_as_float(b & 0xffff0000u);
    a = ya.z; b = yb.z;
    o1.x = w.x * __uint_as_float(a << 16) + w.y * __uint_as_float(b << 16);
    o1.y = w.x * __uint_as_float(a & 0xffff0000u) + w.y * __uint_as_float(b & 0xffff0000u);
    a = ya.w; b = yb.w;
    o1.z = w.x * __uint_as_float(a << 16) + w.y * __uint_as_float(b << 16);
    o1.w = w.x * __uint_as_float(a & 0xffff0000u) + w.y * __uint_as_float(b & 0xffff0000u);
    float4* op = (float4*)(out + (size_t)n * DIM) + tid * 2;
    op[0] = o0; op[1] = o1;
}

extern "C" void kernel_launch(void* const* d_in, const int* in_sizes, int n_in,
                              void* d_out, int out_size, void* d_ws, size_t ws_size,
                              hipStream_t stream) {
    const float* x  = (const float*)d_in[0];   // [N, D]
    const float* Wg = (const float*)d_in[1];   // [D, E]
    const float* We = (const float*)d_in[2];   // [E, D, D]
    const float* be = (const float*)d_in[3];   // [E, D]
    float* out = (float*)d_out;                // [N, D] fp32
    char* ws = (char*)d_ws;
    int*    cnt     = (int*)(ws + OFF_CNT);
    int*    hist    = (int*)(ws + OFF_HIST);
    int*    pre     = (int*)(ws + OFF_PRE);
    int2*   route_e = (int2*)(ws + OFF_RE);
    int4*   route_i = (int4*)(ws + OFF_RI);
    float2* route_w = (float2*)(ws + OFF_RW);
    int*    tok_idx = (int*)(ws + OFF_TIDX);
    u16*    Xb      = (u16*)(ws + OFF_XB);
    u16*    Wt      = (u16*)(ws + OFF_WT);
    u16*    Yp      = (u16*)(ws + OFF_YP);

    k_gate<<<N_TOK / 4, 256, 0, stream>>>(x, Wg, route_e, route_w, Xb);
    k_hist<<<NCHUNK, 256, 0, stream>>>(route_e, hist);
    k_scan<<<1, 64, 0, stream>>>(hist, pre, cnt);
    k_assign<<<NCHUNK, 256, 0, stream>>>(route_e, pre, route_i, tok_idx);
    k_transpose_we<<<dim3(DIM / 64, DIM / 256, NEXP), 256, 0, stream>>>(We, Wt);
    k_moe_gemm<<<dim3(DIM / 128, RPAD / 128, 1), 256, 0, stream>>>(
        Xb, Wt, be, cnt, tok_idx, Yp);
    k_combine<<<N_TOK, 256, 0, stream>>>(Yp, cnt, route_i, route_w, out);
}